// Round 5
// baseline (85.084 us; speedup 1.0000x reference)
//
#include <hip/hip_runtime.h>
#include <cstdint>

// OctantQuery: pcs [B,3,N] f32 -> out [B,N,9,K] int32.
// One wave (64 lanes) handles TWO center points, sharing each chunk's three
// candidate loads between them: total loads and total wave-iterations halve
// vs one-center-per-wave, while distance math (the irreducible work) stays
// constant. Per-center pipeline is identical to the proven baseline:
// ballot(within) -> wave-uniform empty-chunk skip -> SALU octant mask tree
// (14 s_and_b64) -> rank/popcount bookkeeping. Self-exclusion (j != i) is a
// wave-uniform SALU mask clear. blockIdx is swizzled so same-CU blocks
// (stride-256 chains under round-robin dispatch) share one batch -> 24 KB
// CU working set fits 32 KB L1 (vs 96 KB thrash with the natural mapping).

#define NPTS   2048
#define KSAMP  32
#define RAD2   0.16f

__device__ __forceinline__ unsigned rank_below(unsigned long long mask) {
    // number of set bits in `mask` at lane positions strictly below mine
    return __builtin_amdgcn_mbcnt_hi((unsigned)(mask >> 32),
           __builtin_amdgcn_mbcnt_lo((unsigned)(mask & 0xffffffffu), 0u));
}

__global__ __launch_bounds__(256) void octant_query_kernel(
    const float* __restrict__ pcs, int* __restrict__ out) {
#pragma clang fp contract(off)
    const int wid  = (int)(threadIdx.x >> 6);
    const int lane = (int)(threadIdx.x & 63);
    const int m    = (int)blockIdx.x;

    // Batch/pair decode. For the B=4 grid (1024 blocks), pick b from bits
    // [7:6] of blockIdx so the stride-256 same-CU chain {m, m+256, ...}
    // shares one batch (L1-resident working set). Otherwise fall back to the
    // natural mapping. Pure permutation either way.
    int b, pair;
    if (gridDim.x == 1024) {
        const int low = m & 255;
        b    = low >> 6;
        pair = (((m >> 8) << 6) | (low & 63)) * 4 + wid;   // [0, 1024)
    } else {
        const int w = m * 4 + wid;
        b    = w >> 10;                // pairs per batch = NPTS/2 = 1024
        pair = w & 1023;
    }
    const int i0 = pair * 2;
    const int i1 = i0 + 1;

    const float* __restrict__ px = pcs + (size_t)b * 3 * NPTS;
    const float* __restrict__ py = px + NPTS;
    const float* __restrict__ pz = py + NPTS;

    const float cx0 = px[i0], cy0 = py[i0], cz0 = pz[i0];
    const float cx1 = px[i1], cy1 = py[i1], cz1 = pz[i1];

    int* __restrict__ obase0 = out + (size_t)(b * NPTS + i0) * 9 * KSAMP;
    int* __restrict__ obase1 = out + (size_t)(b * NPTS + i1) * 9 * KSAMP;

    const int ichunk0 = i0 >> 6;
    const int ichunk1 = i1 >> 6;
    const unsigned long long notself0 = ~(1ULL << (i0 & 63));
    const unsigned long long notself1 = ~(1ULL << (i1 & 63));

    int cA0 = 0, cA1 = 0, cA2 = 0, cA3 = 0, cA4 = 0, cA5 = 0, cA6 = 0, cA7 = 0;
    int cB0 = 0, cB1 = 0, cB2 = 0, cB3 = 0, cB4 = 0, cB5 = 0, cB6 = 0, cB7 = 0;

#define DO_OCT(ob, o, mexpr, cnt)                                           \
        {                                                                   \
            const unsigned long long mm = (mexpr);                          \
            if (mm) {                             /* uniform skip */        \
                if ((mm >> lane) & 1ULL) {                                  \
                    const int r = cnt + (int)rank_below(mm);                \
                    if (r < KSAMP) (ob)[(o) * KSAMP + r] = j;               \
                }                                                           \
                cnt += (int)__popcll(mm);                                   \
            }                                                               \
        }

#define OCTS(ob, mw, mx, my, mz, c0, c1, c2, c3, c4, c5, c6, c7)            \
        {                                                                   \
            const unsigned long long a0 = (mw) & ~(mx), a1 = (mw) & (mx);   \
            const unsigned long long b0 = a0 & ~(my), b1 = a1 & ~(my);      \
            const unsigned long long b2 = a0 &  (my), b3 = a1 &  (my);      \
            DO_OCT(ob, 0, b0 & ~(mz), c0)                                   \
            DO_OCT(ob, 1, b1 & ~(mz), c1)                                   \
            DO_OCT(ob, 2, b2 & ~(mz), c2)                                   \
            DO_OCT(ob, 3, b3 & ~(mz), c3)                                   \
            DO_OCT(ob, 4, b0 &  (mz), c4)                                   \
            DO_OCT(ob, 5, b1 &  (mz), c5)                                   \
            DO_OCT(ob, 6, b2 &  (mz), c6)                                   \
            DO_OCT(ob, 7, b3 &  (mz), c7)                                   \
        }

    for (int c = 0; c < NPTS; c += 64) {
        // one set of candidate loads serves both centers
        const float xx = px[c + lane];
        const float yy = py[c + lane];
        const float zz = pz[c + lane];

        // match numpy rounding: no fp contraction (pragma above), left-assoc
        const float dx0 = xx - cx0;
        const float dy0 = yy - cy0;
        const float dz0 = zz - cz0;
        float d20 = dx0 * dx0;
        d20 = d20 + dy0 * dy0;
        d20 = d20 + dz0 * dz0;

        const float dx1 = xx - cx1;
        const float dy1 = yy - cy1;
        const float dz1 = zz - cz1;
        float d21 = dx1 * dx1;
        d21 = d21 + dy1 * dy1;
        d21 = d21 + dz1 * dz1;

        unsigned long long mw0 = __ballot(d20 < RAD2);
        unsigned long long mw1 = __ballot(d21 < RAD2);
        const int ch = c >> 6;
        if (ch == ichunk0) mw0 &= notself0;      // wave-uniform self-excl
        if (ch == ichunk1) mw1 &= notself1;
        if ((mw0 | mw1) == 0ULL) continue;       // wave-uniform skip (~55%)

        const int j = c + lane;
        if (mw0) {
            const unsigned long long mx = __ballot(dx0 > 0.f);
            const unsigned long long my = __ballot(dy0 > 0.f);
            const unsigned long long mz = __ballot(dz0 > 0.f);
            OCTS(obase0, mw0, mx, my, mz, cA0, cA1, cA2, cA3, cA4, cA5, cA6, cA7)
        }
        if (mw1) {
            const unsigned long long mx = __ballot(dx1 > 0.f);
            const unsigned long long my = __ballot(dy1 > 0.f);
            const unsigned long long mz = __ballot(dz1 > 0.f);
            OCTS(obase1, mw1, mx, my, mz, cB0, cB1, cB2, cB3, cB4, cB5, cB6, cB7)
        }
    }
#undef OCTS
#undef DO_OCT

    // pad remaining slots with the center index (each slot written once)
#define FILL(ob, idx, o, cnt)                                               \
        {                                                                   \
            const int s = cnt + lane;                                       \
            if (s < KSAMP) (ob)[(o) * KSAMP + s] = idx;                     \
        }
    FILL(obase0, i0, 0, cA0) FILL(obase0, i0, 1, cA1)
    FILL(obase0, i0, 2, cA2) FILL(obase0, i0, 3, cA3)
    FILL(obase0, i0, 4, cA4) FILL(obase0, i0, 5, cA5)
    FILL(obase0, i0, 6, cA6) FILL(obase0, i0, 7, cA7)
    FILL(obase1, i1, 0, cB0) FILL(obase1, i1, 1, cB1)
    FILL(obase1, i1, 2, cB2) FILL(obase1, i1, 3, cB3)
    FILL(obase1, i1, 4, cB4) FILL(obase1, i1, 5, cB5)
    FILL(obase1, i1, 6, cB6) FILL(obase1, i1, 7, cB7)
#undef FILL
    if (lane < KSAMP) {
        obase0[8 * KSAMP + lane] = i0;
        obase1[8 * KSAMP + lane] = i1;
    }
}

extern "C" void kernel_launch(void* const* d_in, const int* in_sizes, int n_in,
                              void* d_out, int out_size, void* d_ws, size_t ws_size,
                              hipStream_t stream) {
    const float* pcs = (const float*)d_in[0];
    int* out = (int*)d_out;
    const int B = in_sizes[0] / (3 * NPTS);       // 4
    const int npairs = B * NPTS / 2;              // two centers per wave
    const int block = 256;                        // 4 waves/block
    const int grid = npairs / 4;                  // 8 centers per block
    octant_query_kernel<<<grid, block, 0, stream>>>(pcs, out);
}

// Round 6
// 70.310 us; speedup vs baseline: 1.2101x; 1.2101x over previous
//
#include <hip/hip_runtime.h>
#include <cstdint>

// OctantQuery: pcs [B,3,N] f32 -> out [B,N,9,K] int32.
// EXACT R0 structure (proven best: one wave per center, 64-candidate chunks,
// ballot + wave-uniform empty skip + SALU octant masks). Single change vs
// R0: batch index is taken from the LOW 2 bits of blockIdx instead of the
// high bits, so the same-CU block chain {m, m+256, ...} under round-robin
// dispatch reads ONE batch (24 KB, L1-resident) instead of all four (96 KB,
// L1 thrash). Pure index permutation: loop body, register pressure, and
// store pattern are byte-identical to R0.

#define NPTS   2048
#define KSAMP  32
#define RAD2   0.16f

__device__ __forceinline__ unsigned rank_below(unsigned long long mask) {
    // number of set bits in `mask` at lane positions strictly below mine
    return __builtin_amdgcn_mbcnt_hi((unsigned)(mask >> 32),
           __builtin_amdgcn_mbcnt_lo((unsigned)(mask & 0xffffffffu), 0u));
}

__global__ __launch_bounds__(256) void octant_query_kernel(
    const float* __restrict__ pcs, int* __restrict__ out, int nblocks) {
#pragma clang fp contract(off)
    const int wid  = (int)(threadIdx.x >> 6);
    const int lane = (int)(threadIdx.x & 63);
    const int m    = (int)blockIdx.x;
    if (m >= nblocks) return;

    // L1-locality swizzle: b from low bits -> same-CU chain shares a batch.
    const int b = m & 3;
    const int i = (m >> 2) * 4 + wid;       // bijective over [0, NPTS) per b

    const float* __restrict__ px = pcs + (size_t)b * 3 * NPTS;
    const float* __restrict__ py = px + NPTS;
    const float* __restrict__ pz = py + NPTS;

    const float cx = px[i];
    const float cy = py[i];
    const float cz = pz[i];

    int* __restrict__ obase = out + (size_t)(b * NPTS + i) * 9 * KSAMP;

    int cnt0 = 0, cnt1 = 0, cnt2 = 0, cnt3 = 0;
    int cnt4 = 0, cnt5 = 0, cnt6 = 0, cnt7 = 0;

    for (int c = 0; c < NPTS; c += 64) {
        const int j = c + lane;
        const float dx = px[j] - cx;
        const float dy = py[j] - cy;
        const float dz = pz[j] - cz;
        // match numpy rounding: no fp contraction (pragma above), left-assoc
        float d2 = dx * dx;
        d2 = d2 + dy * dy;
        d2 = d2 + dz * dz;
        const bool within = (d2 < RAD2) && (j != i);
        const unsigned long long mw = __ballot(within);
        if (mw == 0ULL) continue;                 // wave-uniform skip (~70%)

        const unsigned long long mx = __ballot(dx > 0.f);
        const unsigned long long my = __ballot(dy > 0.f);
        const unsigned long long mz = __ballot(dz > 0.f);

#define DO_OCT(o, cnt)                                                      \
        {                                                                   \
            unsigned long long mm = mw;                                     \
            mm &= ((o) & 1) ? mx : ~mx;                                     \
            mm &= ((o) & 2) ? my : ~my;                                     \
            mm &= ((o) & 4) ? mz : ~mz;                                     \
            if (mm) {                             /* uniform skip */        \
                const bool mine = (mm >> lane) & 1ULL;                      \
                if (mine) {                                                 \
                    const int r = cnt + (int)rank_below(mm);                \
                    if (r < KSAMP) obase[(o) * KSAMP + r] = j;              \
                }                                                           \
                cnt += (int)__popcll(mm);                                   \
            }                                                               \
        }
        DO_OCT(0, cnt0) DO_OCT(1, cnt1) DO_OCT(2, cnt2) DO_OCT(3, cnt3)
        DO_OCT(4, cnt4) DO_OCT(5, cnt5) DO_OCT(6, cnt6) DO_OCT(7, cnt7)
#undef DO_OCT
    }

    // pad remaining slots with center index i (each slot written exactly once)
#define FILL(o, cnt)                                                        \
        {                                                                   \
            const int s = cnt + lane;                                       \
            if (s < KSAMP) obase[(o) * KSAMP + s] = i;                      \
        }
    FILL(0, cnt0) FILL(1, cnt1) FILL(2, cnt2) FILL(3, cnt3)
    FILL(4, cnt4) FILL(5, cnt5) FILL(6, cnt6) FILL(7, cnt7)
#undef FILL
    if (lane < KSAMP) obase[8 * KSAMP + lane] = i;
}

extern "C" void kernel_launch(void* const* d_in, const int* in_sizes, int n_in,
                              void* d_out, int out_size, void* d_ws, size_t ws_size,
                              hipStream_t stream) {
    const float* pcs = (const float*)d_in[0];
    int* out = (int*)d_out;
    const int B = in_sizes[0] / (3 * NPTS);   // 4
    const int nblocks = B * NPTS / 4;         // one wave per center, 4/block
    const int block = 256;
    octant_query_kernel<<<nblocks, block, 0, stream>>>(pcs, out, nblocks);
}